// Round 8
// baseline (3404.672 us; speedup 1.0000x reference)
//
#include <hip/hip_runtime.h>
#include <stdint.h>

// B=32, L=256, D=128. Reader LSTM scan + attention-memory writer scan. FP32.
// Inputs: x(32,256,128), Wr(128,512), Ur(128,512), br(512),
//         Ww(128,512), Uw(128,512), bw(512), Wc(256,128), bc(128)
// Output: final writer h (32,128) fp32.
//
// v8 = v5 base + register-NEUTRAL critical-path cuts. Register law learned
// from v2/v5/v6/v7: Mr64+Mc64 is the budget; any extra weight-in-regs plan
// spills (v6/v7) or gets rematerialized (v5; FETCH identical v4/v5/v7).
//  (a) single-pass softmax (v7): per-wave max+exp+sum, global fold via
//      per-thread f = exp(m_wave - M). (S3 group wave == S7 row wave ==
//      tid>>7 -> one f.)  -1 barrier.
//  (b) quad-gate fusion: thread computes z column jmap=(tid>>2)+((tid&3)<<7)
//      so a column's 4 gate components sit in 4 ADJACENT LANES -> 3 shfl_xor
//      + selects compute gates in-register right after S5's dot. No pp_s
//      round-trip, no S6 stage. c_w replicated x4/quad (bit-identical).
//      UwL stored XOR-swizzled ((kk^g)+(g<<7)) to keep LDS reads ~2-way.
//      -1 barrier, -1 stage.
//  (c) 8-tile Vw early prefetch (32 transient regs, issued after S0,
//      consumed in S5) — hides ~64KB of the Vw stream behind softmax+S3+S4.
//  (d) ZW row prefetched one step ahead (1 reg). NO VR[16].
// Barriers/step: 7 -> 5. WRITE_SIZE = spill canary (must be 16KB).
// Workspace: 5.70M floats = 22.8MB (ZW aliases XW; XW dead after reader).

#define LL 256

typedef float v2f __attribute__((ext_vector_type(2)));

__device__ __forceinline__ float hsig(float x) { return fminf(fmaxf(fmaf(x, 0.2f, 0.5f), 0.f), 1.f); }
__device__ __forceinline__ float tanh_fast(float x) {
  x = fminf(fmaxf(x, -15.f), 15.f);
  float e = __expf(2.f * x);
  return (e - 1.f) / (e + 1.f);
}

// ---- Prep: transpose fp32 W[K][J] (row-major) -> float4 k-tiles ----------
// dst float4 index (k>>2)*J + j holds rows k..k+3 of column j.
__global__ __launch_bounds__(512) void wtrans_kernel(const float* __restrict__ src,
                                                     float* __restrict__ dst, int jshift) {
  int idx = blockIdx.x * 512 + threadIdx.x;
  int J = 1 << jshift;
  int k = idx >> jshift, j = idx & (J - 1);
  dst[(((size_t)(k >> 2) << jshift) + j) * 4 + (k & 3)] = src[idx];
}

// ---- PVw[r][j] = Wc[r][:] @ Ww[:,j]  (r<128: Pw=Wc_top@Ww, r>=128: Vw) ----
__global__ __launch_bounds__(512) void pvw_gemm(const float* __restrict__ Wc,
                                                const float* __restrict__ Ww,
                                                float* __restrict__ PVw) {
  __shared__ float wrow[128];
  const int r = blockIdx.x, j = threadIdx.x;
  if (j < 128) wrow[j] = Wc[r * 128 + j];
  __syncthreads();
  float a = 0.f;
#pragma unroll 4
  for (int m = 0; m < 128; m++) a = fmaf(wrow[m], Ww[m * 512 + j], a);
  PVw[r * 512 + j] = a;
}

// ---- pz[j] = bc @ Ww[:,j] + bw[j] -----------------------------------------
__global__ __launch_bounds__(512) void pz_kernel(const float* __restrict__ bc,
                                                 const float* __restrict__ Ww,
                                                 const float* __restrict__ bw,
                                                 float* __restrict__ pz) {
  __shared__ float b_s[128];
  const int j = threadIdx.x;
  if (j < 128) b_s[j] = bc[j];
  __syncthreads();
  float a = bw[j];
#pragma unroll 4
  for (int m = 0; m < 128; m++) a = fmaf(b_s[m], Ww[m * 512 + j], a);
  pz[j] = a;
}

// ---- GEMM: OUT[b,t,:] = IN[b,t,:] @ W(T4 tiles, K=128,J=512) + bias -------
// Used for XW = x@Wr + br  and  ZW = og@Pw + pz.
__global__ __launch_bounds__(512) void xw_gemm(const float* __restrict__ x,
                                               const float4* __restrict__ WrT4,
                                               const float* __restrict__ br,
                                               float* __restrict__ XW) {
  alignas(16) __shared__ float xs[8][128];
  const int b = blockIdx.x >> 5, tg = blockIdx.x & 31, tid = threadIdx.x;
  const float* xg = x + ((size_t)b * LL + tg * 8) * 128;
  if (tid < 256) ((float4*)&xs[0][0])[tid] = ((const float4*)xg)[tid];
  __syncthreads();
  float acc[8];
#pragma unroll
  for (int r = 0; r < 8; r++) acc[r] = 0.f;
#pragma unroll 8
  for (int i4 = 0; i4 < 32; i4++) {
    float4 w4 = WrT4[i4 * 512 + tid];
#pragma unroll
    for (int r = 0; r < 8; r++) {
      float4 v = *(const float4*)&xs[r][4 * i4];
      acc[r] += w4.x * v.x + w4.y * v.y + w4.z * v.z + w4.w * v.w;
    }
  }
  const float brj = br[tid];
  float* o = XW + ((size_t)b * LL + tg * 8) * 512;
#pragma unroll
  for (int r = 0; r < 8; r++) o[r * 512 + tid] = acc[r] + brj;
}

// ---- Reader: sequential LSTM scan, Ur register-resident -------------------
__global__ __launch_bounds__(512, 2) void reader_kernel(const float4* __restrict__ UrT4,
                                                        const float* __restrict__ XW,
                                                        float* __restrict__ og) {
  alignas(16) __shared__ float h_s[128];
  alignas(16) __shared__ float pp_s[512];
  const int b = blockIdx.x, tid = threadIdx.x;
  const float* XWb = XW + (size_t)b * LL * 512;
  float* ogb = og + (size_t)b * LL * 128;

  float4 U[32];  // column tid of Ur, held for the whole scan (128 VGPRs)
#pragma unroll
  for (int i4 = 0; i4 < 32; i4++) U[i4] = UrT4[i4 * 512 + tid];

  float c_r = 0.f;
  if (tid < 128) h_s[tid] = 0.f;
  float xwv = XWb[tid];  // z-row for t=0 (x@Wr + br precomputed)
  __syncthreads();

  for (int t = 0; t < LL; t++) {
    float xw_n = (t + 1 < LL) ? XWb[(t + 1) * 512 + tid] : 0.f;  // prefetch
    v2f acc[4] = {{0.f, 0.f}, {0.f, 0.f}, {0.f, 0.f}, {0.f, 0.f}};
#pragma unroll
    for (int i4 = 0; i4 < 32; i4++) {  // full unroll: U[i4] must stay static
      float4 v = *(const float4*)&h_s[4 * i4];
      float4 w = U[i4];
      acc[i4 & 3] += (v2f){w.x, w.y} * (v2f){v.x, v.y};
      acc[i4 & 3] += (v2f){w.z, w.w} * (v2f){v.z, v.w};
    }
    v2f A = (acc[0] + acc[1]) + (acc[2] + acc[3]);
    pp_s[tid] = A.x + A.y + xwv;
    __syncthreads();
    if (tid < 128) {
      float zi = pp_s[tid], zf = pp_s[128 + tid], zg = pp_s[256 + tid], zo = pp_s[384 + tid];
      float ii = hsig(zi), ff = hsig(zf), gg = tanh_fast(zg), oo = hsig(zo);
      c_r = fmaf(ff, c_r, ii * gg);
      float h = oo * tanh_fast(c_r);
      h_s[tid] = h;
      ogb[t * 128 + tid] = h;
    }
    __syncthreads();
    xwv = xw_n;
  }
}

// ---- Writer: attention-memory scan ---------------------------------------
// z = ZW_t + m_rt@Vw + h@Uw. Thread owns z column jmap=(tid>>2)+((tid&3)<<7)
// so a column's 4 gate components live in one lane-quad. Uw: [0,NC) LDS
// (XOR-swizzled) + [NC,32) L2. Vw: 8-tile early prefetch + 24 streamed.
template <int NC>
__global__ __launch_bounds__(512, 2) void writer_kernel(
    const float* __restrict__ x,
    const float4* __restrict__ VwT4, const float4* __restrict__ UwT4,
    const float* __restrict__ og, const float* __restrict__ ZW,
    float* __restrict__ out) {
  alignas(16) __shared__ float h_s[128];
  alignas(16) __shared__ float osN[128];   // o_{t+1} (o_0 during prologue)
  alignas(16) __shared__ float sc_s[256], ee_s[256];
  alignas(16) __shared__ float mr_s[128];  // RAW col sums (no inv)
  alignas(16) __shared__ float pp_s[1024];
  __shared__ float rr_s[16];               // [0..3] wave max, [8..11] wave sum
  extern __shared__ float4 UwL[];          // NC*512 float4 Uw cache (swizzled)

  const int b = blockIdx.x, tid = threadIdx.x;
  const int lane = tid & 63, wv = tid >> 6;
  const int l = tid >> 1, hf = tid & 1;    // row-major role
  const int q = tid >> 6, dp = tid & 63;   // col-major role
  const int kk = tid >> 2, g = tid & 3;    // quad role: column kk, gate g
  const int jmap = kk + (g << 7);          // owned z column
  const int jswz = (kk ^ g) + (g << 7);    // swizzled UwL column (bank-spread)

  const float* xg = x + (size_t)b * (LL * 128);
  const float* ogb = og + (size_t)b * (LL * 128);
  const float* ZWb = ZW + (size_t)b * (LL * 512);

  // stage Uw k-tiles [0,NC) into LDS once, XOR-swizzled: column j stored at
  // (j^(j>>7)) + ... so a quad's 4 reads hit different bank groups.
  for (int i = tid; i < NC * 512; i += 512) {
    int i4 = i >> 9, j = i & 511, gj = j >> 7;
    UwL[(i4 << 9) + (j ^ gj)] = UwT4[i];
  }

  // register-resident mem, two layouts (fp32 pairs) — THE register budget.
  v2f Mr[32], Mc[32];
#pragma unroll
  for (int w = 0; w < 32; w++) Mr[w] = *(const v2f*)(xg + l * 128 + hf * 64 + 2 * w);
#pragma unroll
  for (int i = 0; i < 32; i++) Mc[i] = *(const v2f*)(xg + (q * 32 + i) * 128 + 2 * dp);

  float c_w = 0.f;  // replicated per quad (all 4 lanes carry column kk's c)
  if (tid < 128) { h_s[tid] = 0.f; osN[tid] = ogb[tid]; }
  __syncthreads();
  { // prologue: sc_s[l] = mem0[l] . o_0
    v2f S = {0.f, 0.f};
#pragma unroll
    for (int w = 0; w < 32; w++) S += Mr[w] * (*(const v2f*)&osN[hf * 64 + 2 * w]);
    float s = S.x + S.y;
    s += __shfl_xor(s, 1);
    if (hf == 0) sc_s[l] = s;
  }
  __syncthreads();

  float zwv = ZWb[jmap];  // ZW row for t=0, owned column
  for (int t = 0; t < LL; t++) {
    const int tn = (t + 1 < LL) ? t + 1 : t;
    float zw_n = ZWb[(size_t)tn * 512 + jmap];  // prefetch next ZW row

    // S0: huv = zwv + h_{t-1}@Uw — NC LDS tiles + (32-NC) streamed L2 tiles.
    float huv;
    {
      v2f u0 = {0.f, 0.f}, u1 = {0.f, 0.f}, u2 = {0.f, 0.f}, u3 = {0.f, 0.f};
#pragma unroll 2
      for (int i4 = NC; i4 < 32; i4 += 2) {  // streamed Uw (L2)
        float4 w0 = UwT4[i4 * 512 + jmap];
        float4 w1 = UwT4[(i4 + 1) * 512 + jmap];
        float4 v0 = *(const float4*)&h_s[4 * i4];
        float4 v1 = *(const float4*)&h_s[4 * i4 + 4];
        u0 += (v2f){w0.x, w0.y} * (v2f){v0.x, v0.y};
        u0 += (v2f){w0.z, w0.w} * (v2f){v0.z, v0.w};
        u1 += (v2f){w1.x, w1.y} * (v2f){v1.x, v1.y};
        u1 += (v2f){w1.z, w1.w} * (v2f){v1.z, v1.w};
      }
#pragma unroll 2
      for (int i4 = 0; i4 < NC; i4++) {  // cached Uw (LDS, swizzled)
        float4 w = UwL[(i4 << 9) + jswz];
        float4 v = *(const float4*)&h_s[4 * i4];
        u2 += (v2f){w.x, w.y} * (v2f){v.x, v.y};
        u3 += (v2f){w.z, w.w} * (v2f){v.z, v.w};
      }
      v2f U = (u0 + u1) + (u2 + u3);
      huv = U.x + U.y + zwv;
    }

    // early Vw prefetch: tiles 0..7 issued now, consumed in S5 (hides ~64KB
    // of the Vw stream behind softmax+S3+S4; compiler may sink if tight).
    float4 pf0 = VwT4[0 * 512 + jmap], pf1 = VwT4[1 * 512 + jmap];
    float4 pf2 = VwT4[2 * 512 + jmap], pf3 = VwT4[3 * 512 + jmap];
    float4 pf4 = VwT4[4 * 512 + jmap], pf5 = VwT4[5 * 512 + jmap];
    float4 pf6 = VwT4[6 * 512 + jmap], pf7 = VwT4[7 * 512 + jmap];

    // A: single-pass local softmax (per-wave max + exp + sum) ∥ osN load
    if (tid >= 128 && tid < 256 && t + 1 < LL)
      osN[tid - 128] = ogb[(t + 1) * 128 + (tid - 128)];
    if (tid < 256) {
      float s = sc_s[tid];
      float m = s;
#pragma unroll
      for (int off = 32; off > 0; off >>= 1) m = fmaxf(m, __shfl_xor(m, off));
      float e = __expf(s - m);   // wave-relative exp, <= 1
      ee_s[tid] = e;             // RAW (wave-relative) — consumers apply f
      float s2 = e;
#pragma unroll
      for (int off = 32; off > 0; off >>= 1) s2 += __shfl_xor(s2, off);
      if (lane == 0) { rr_s[wv] = m; rr_s[8 + wv] = s2; }
    }
    __syncthreads();

    // B: fold global max/sum; per-thread factor f (wave tid>>7 of sc-space —
    // serves BOTH S3's group (q>>1) and S7's row (l>>6), which equal tid>>7).
    const float M = fmaxf(fmaxf(rr_s[0], rr_s[1]), fmaxf(rr_s[2], rr_s[3]));
    const float Sg = rr_s[8] * __expf(rr_s[0] - M) + rr_s[9] * __expf(rr_s[1] - M) +
                     rr_s[10] * __expf(rr_s[2] - M) + rr_s[11] * __expf(rr_s[3] - M);
    const float inv = 1.f / Sg;
    const float f = __expf(rr_s[tid >> 7] - M);
    const float fzi = f * inv;

    // S3: m_rt partials (col-major, register-local), 2 chains, scaled by f
    {
      v2f P0 = {0.f, 0.f}, P1 = {0.f, 0.f};
#pragma unroll
      for (int i = 0; i < 32; i += 2) {
        P0 += Mc[i] * ee_s[q * 32 + i];
        P1 += Mc[i + 1] * ee_s[q * 32 + i + 1];
      }
      v2f P = (P0 + P1) * f;
      *(v2f*)&pp_s[q * 128 + 2 * dp] = P;
    }
    __syncthreads();
    // S4: raw m_rt (inv folded later, scalar, in S5)
    if (tid < 128) {
      float s = 0.f;
#pragma unroll
      for (int g8 = 0; g8 < 8; g8++) s += pp_s[g8 * 128 + tid];
      mr_s[tid] = s;
    }
    __syncthreads();
    // S5+gates: zv = huv + inv*(mraw@Vw); quad-shfl -> gates -> h_s. No S6.
    {
      v2f a0 = {0.f, 0.f}, a1 = {0.f, 0.f}, a2 = {0.f, 0.f}, a3 = {0.f, 0.f};
#pragma unroll 2
      for (int i4 = 8; i4 < 32; i4 += 2) {  // streamed Vw (L2)
        float4 w0 = VwT4[i4 * 512 + jmap];
        float4 w1 = VwT4[(i4 + 1) * 512 + jmap];
        float4 v0 = *(const float4*)&mr_s[4 * i4];
        float4 v1 = *(const float4*)&mr_s[4 * i4 + 4];
        a0 += (v2f){w0.x, w0.y} * (v2f){v0.x, v0.y};
        a0 += (v2f){w0.z, w0.w} * (v2f){v0.z, v0.w};
        a1 += (v2f){w1.x, w1.y} * (v2f){v1.x, v1.y};
        a1 += (v2f){w1.z, w1.w} * (v2f){v1.z, v1.w};
      }
      {  // prefetched tiles 0..7
        float4 m0 = *(const float4*)&mr_s[0],  m1 = *(const float4*)&mr_s[4];
        float4 m2 = *(const float4*)&mr_s[8],  m3 = *(const float4*)&mr_s[12];
        float4 m4 = *(const float4*)&mr_s[16], m5 = *(const float4*)&mr_s[20];
        float4 m6 = *(const float4*)&mr_s[24], m7 = *(const float4*)&mr_s[28];
        a2 += (v2f){pf0.x, pf0.y} * (v2f){m0.x, m0.y}; a2 += (v2f){pf0.z, pf0.w} * (v2f){m0.z, m0.w};
        a3 += (v2f){pf1.x, pf1.y} * (v2f){m1.x, m1.y}; a3 += (v2f){pf1.z, pf1.w} * (v2f){m1.z, m1.w};
        a2 += (v2f){pf2.x, pf2.y} * (v2f){m2.x, m2.y}; a2 += (v2f){pf2.z, pf2.w} * (v2f){m2.z, m2.w};
        a3 += (v2f){pf3.x, pf3.y} * (v2f){m3.x, m3.y}; a3 += (v2f){pf3.z, pf3.w} * (v2f){m3.z, m3.w};
        a2 += (v2f){pf4.x, pf4.y} * (v2f){m4.x, m4.y}; a2 += (v2f){pf4.z, pf4.w} * (v2f){m4.z, m4.w};
        a3 += (v2f){pf5.x, pf5.y} * (v2f){m5.x, m5.y}; a3 += (v2f){pf5.z, pf5.w} * (v2f){m5.z, m5.w};
        a2 += (v2f){pf6.x, pf6.y} * (v2f){m6.x, m6.y}; a2 += (v2f){pf6.z, pf6.w} * (v2f){m6.z, m6.w};
        a3 += (v2f){pf7.x, pf7.y} * (v2f){m7.x, m7.y}; a3 += (v2f){pf7.z, pf7.w} * (v2f){m7.z, m7.w};
      }
      v2f A = (a0 + a2) + (a1 + a3);
      float zv = fmaf(A.x + A.y, inv, huv);
      // quad exchange: lane g ends with arr[x] = z[g^x]
      float sv1 = __shfl_xor(zv, 1);
      float sv2 = __shfl_xor(zv, 2);
      float sv3 = __shfl_xor(sv1, 2);
      float zi = (g == 0) ? zv : (g == 1) ? sv1 : (g == 2) ? sv2 : sv3;
      float zf = (g == 1) ? zv : (g == 0) ? sv1 : (g == 3) ? sv2 : sv3;
      float zg = (g == 2) ? zv : (g == 3) ? sv1 : (g == 0) ? sv2 : sv3;
      float zo = (g == 3) ? zv : (g == 2) ? sv1 : (g == 1) ? sv2 : sv3;
      float ii = hsig(zi), ff = hsig(zf), gg2 = tanh_fast(zg), oo = hsig(zo);
      c_w = fmaf(ff, c_w, ii * gg2);
      float hh = oo * tanh_fast(c_w);
      if (g == 0) h_s[kk] = hh;
    }
    __syncthreads();
    // S7: mem update (both layouts, bit-identical z = ee*fzi) + next scores
    if (t + 1 < LL) {
      const float zr = ee_s[l] * fzi;
      v2f S0v = {0.f, 0.f}, S1v = {0.f, 0.f};
#pragma unroll
      for (int w = 0; w < 32; w += 2) {
        v2f h2a = *(const v2f*)&h_s[hf * 64 + 2 * w];
        v2f ma = Mr[w];
        v2f na = ma + (h2a - ma) * zr;
        Mr[w] = na;
        S0v += na * (*(const v2f*)&osN[hf * 64 + 2 * w]);
        v2f h2b = *(const v2f*)&h_s[hf * 64 + 2 * (w + 1)];
        v2f mb = Mr[w + 1];
        v2f nb = mb + (h2b - mb) * zr;
        Mr[w + 1] = nb;
        S1v += nb * (*(const v2f*)&osN[hf * 64 + 2 * (w + 1)]);
      }
      v2f Sv = S0v + S1v;
      float s = Sv.x + Sv.y;
      s += __shfl_xor(s, 1);
      if (hf == 0) sc_s[l] = s;
      v2f hc = *(const v2f*)&h_s[2 * dp];
#pragma unroll
      for (int i = 0; i < 32; i++) {
        float zc = ee_s[q * 32 + i] * fzi;  // same expr shape as zr
        v2f m = Mc[i];
        Mc[i] = m + (hc - m) * zc;
      }
    }
    __syncthreads();
    zwv = zw_n;
  }

  if (tid < 128) out[b * 128 + tid] = h_s[tid];
}

extern "C" void kernel_launch(void* const* d_in, const int* in_sizes, int n_in,
                              void* d_out, int out_size, void* d_ws, size_t ws_size,
                              hipStream_t stream) {
  const float* x  = (const float*)d_in[0];
  const float* Wr = (const float*)d_in[1];
  const float* Ur = (const float*)d_in[2];
  const float* br = (const float*)d_in[3];
  const float* Ww = (const float*)d_in[4];
  const float* Uw = (const float*)d_in[5];
  const float* bw = (const float*)d_in[6];
  const float* Wc = (const float*)d_in[7];
  const float* bc = (const float*)d_in[8];
  float* out = (float*)d_out;

  // workspace (floats): og 1,048,576 | XW/ZW 4,194,304 | WrT 65,536 |
  // UrT 65,536 | UwT 65,536 | PVw 131,072 | PwT 65,536 | VwT 65,536 | pz 512
  // total 5,702,656 floats = 22.8 MB
  float* og  = (float*)d_ws;
  float* XW  = og + 1048576;   // ZW aliases XW (XW dead after reader)
  float* WrT = XW + 4194304;
  float* UrT = WrT + 65536;
  float* UwT = UrT + 65536;
  float* PVw = UwT + 65536;
  float* PwT = PVw + 131072;
  float* VwT = PwT + 65536;
  float* pz  = VwT + 65536;

  // big-LDS opt-in for the Uw cache (capture-safe: not a stream op).
  static int nc_cached = -1;
  if (nc_cached < 0) {
    int want = 18 * 512 * (int)sizeof(float4);  // 147456 B dynamic
    nc_cached = (hipFuncSetAttribute(
                     reinterpret_cast<const void*>(&writer_kernel<18>),
                     hipFuncAttributeMaxDynamicSharedMemorySize, want) == hipSuccess)
                    ? 18
                    : 6;  // fallback: 48KB dynamic, under default 64KB limit
  }

  wtrans_kernel<<<128, 512, 0, stream>>>(Wr, WrT, 9);
  wtrans_kernel<<<128, 512, 0, stream>>>(Ur, UrT, 9);
  wtrans_kernel<<<128, 512, 0, stream>>>(Uw, UwT, 9);
  pvw_gemm<<<256, 512, 0, stream>>>(Wc, Ww, PVw);
  pz_kernel<<<1, 512, 0, stream>>>(bc, Ww, bw, pz);
  wtrans_kernel<<<128, 512, 0, stream>>>(PVw, PwT, 9);
  wtrans_kernel<<<128, 512, 0, stream>>>(PVw + 65536, VwT, 9);
  xw_gemm<<<1024, 512, 0, stream>>>(x, (const float4*)WrT, br, XW);
  reader_kernel<<<32, 512, 0, stream>>>((const float4*)UrT, XW, og);
  xw_gemm<<<1024, 512, 0, stream>>>(og, (const float4*)PwT, pz, XW);  // ZW
  if (nc_cached == 18) {
    writer_kernel<18><<<32, 512, 18 * 512 * sizeof(float4), stream>>>(
        x, (const float4*)VwT, (const float4*)UwT, og, XW, out);
  } else {
    writer_kernel<6><<<32, 512, 6 * 512 * sizeof(float4), stream>>>(
        x, (const float4*)VwT, (const float4*)UwT, og, XW, out);
  }
}

// Round 9
// 2516.532 us; speedup vs baseline: 1.3529x; 1.3529x over previous
//
#include <hip/hip_runtime.h>
#include <stdint.h>

// B=32, L=256, D=128. Reader LSTM scan + attention-memory writer scan. FP32.
// Inputs: x(32,256,128), Wr(128,512), Ur(128,512), br(512),
//         Ww(128,512), Uw(128,512), bw(512), Wc(256,128), bc(128)
// Output: final writer h (32,128) fp32.
//
// v9: writer rebuilt at 1024 threads (16 waves/CU; was 8). The step is
// latency-bound (v5: byte cuts gained nothing; v8's coalescing-breaking quad
// map cost 2x). Every j-dot splits its k-range across two halves
// (j=tid&511, half=tid>>9, parity-interleaved tiles); halves merge in the
// gate stage via pp_s[half*512+j] (no extra barrier). mem = Mr[16]+Mc[16]
// per thread (64 VGPRs persistent, fits 128-cap at 16 waves/CU); S7 chain
// halves. Single-pass softmax (v7) + ZW prefetch kept; 6 barriers/step.
// All global loads indexed by plain j -> coalesced (v8 lesson).
// One fzi = exp(rr_s[tid>>8]-M)*inv serves S3/Mr/Mc (both row-block maps
// land on tid>>8) — v5's bit-exact update expression preserved.
// Register law (v2/v6/v7): mem only; weights live in LDS or L2.
// WRITE_SIZE = spill canary (must stay 16KB).
// Workspace: 5.70M floats = 22.8MB (ZW aliases XW; XW dead after reader).

#define LL 256

typedef float v2f __attribute__((ext_vector_type(2)));

__device__ __forceinline__ float hsig(float x) { return fminf(fmaxf(fmaf(x, 0.2f, 0.5f), 0.f), 1.f); }
__device__ __forceinline__ float tanh_fast(float x) {
  x = fminf(fmaxf(x, -15.f), 15.f);
  float e = __expf(2.f * x);
  return (e - 1.f) / (e + 1.f);
}

// ---- Prep: transpose fp32 W[K][J] (row-major) -> float4 k-tiles ----------
// dst float4 index (k>>2)*J + j holds rows k..k+3 of column j.
__global__ __launch_bounds__(512) void wtrans_kernel(const float* __restrict__ src,
                                                     float* __restrict__ dst, int jshift) {
  int idx = blockIdx.x * 512 + threadIdx.x;
  int J = 1 << jshift;
  int k = idx >> jshift, j = idx & (J - 1);
  dst[(((size_t)(k >> 2) << jshift) + j) * 4 + (k & 3)] = src[idx];
}

// ---- PVw[r][j] = Wc[r][:] @ Ww[:,j]  (r<128: Pw=Wc_top@Ww, r>=128: Vw) ----
__global__ __launch_bounds__(512) void pvw_gemm(const float* __restrict__ Wc,
                                                const float* __restrict__ Ww,
                                                float* __restrict__ PVw) {
  __shared__ float wrow[128];
  const int r = blockIdx.x, j = threadIdx.x;
  if (j < 128) wrow[j] = Wc[r * 128 + j];
  __syncthreads();
  float a = 0.f;
#pragma unroll 4
  for (int m = 0; m < 128; m++) a = fmaf(wrow[m], Ww[m * 512 + j], a);
  PVw[r * 512 + j] = a;
}

// ---- pz[j] = bc @ Ww[:,j] + bw[j] -----------------------------------------
__global__ __launch_bounds__(512) void pz_kernel(const float* __restrict__ bc,
                                                 const float* __restrict__ Ww,
                                                 const float* __restrict__ bw,
                                                 float* __restrict__ pz) {
  __shared__ float b_s[128];
  const int j = threadIdx.x;
  if (j < 128) b_s[j] = bc[j];
  __syncthreads();
  float a = bw[j];
#pragma unroll 4
  for (int m = 0; m < 128; m++) a = fmaf(b_s[m], Ww[m * 512 + j], a);
  pz[j] = a;
}

// ---- GEMM: OUT[b,t,:] = IN[b,t,:] @ W(T4 tiles, K=128,J=512) + bias -------
// Used for XW = x@Wr + br  and  ZW = og@Pw + pz.
__global__ __launch_bounds__(512) void xw_gemm(const float* __restrict__ x,
                                               const float4* __restrict__ WrT4,
                                               const float* __restrict__ br,
                                               float* __restrict__ XW) {
  alignas(16) __shared__ float xs[8][128];
  const int b = blockIdx.x >> 5, tg = blockIdx.x & 31, tid = threadIdx.x;
  const float* xg = x + ((size_t)b * LL + tg * 8) * 128;
  if (tid < 256) ((float4*)&xs[0][0])[tid] = ((const float4*)xg)[tid];
  __syncthreads();
  float acc[8];
#pragma unroll
  for (int r = 0; r < 8; r++) acc[r] = 0.f;
#pragma unroll 8
  for (int i4 = 0; i4 < 32; i4++) {
    float4 w4 = WrT4[i4 * 512 + tid];
#pragma unroll
    for (int r = 0; r < 8; r++) {
      float4 v = *(const float4*)&xs[r][4 * i4];
      acc[r] += w4.x * v.x + w4.y * v.y + w4.z * v.z + w4.w * v.w;
    }
  }
  const float brj = br[tid];
  float* o = XW + ((size_t)b * LL + tg * 8) * 512;
#pragma unroll
  for (int r = 0; r < 8; r++) o[r * 512 + tid] = acc[r] + brj;
}

// ---- Reader: sequential LSTM scan, Ur register-resident -------------------
__global__ __launch_bounds__(512, 2) void reader_kernel(const float4* __restrict__ UrT4,
                                                        const float* __restrict__ XW,
                                                        float* __restrict__ og) {
  alignas(16) __shared__ float h_s[128];
  alignas(16) __shared__ float pp_s[512];
  const int b = blockIdx.x, tid = threadIdx.x;
  const float* XWb = XW + (size_t)b * LL * 512;
  float* ogb = og + (size_t)b * LL * 128;

  float4 U[32];  // column tid of Ur, held for the whole scan (128 VGPRs)
#pragma unroll
  for (int i4 = 0; i4 < 32; i4++) U[i4] = UrT4[i4 * 512 + tid];

  float c_r = 0.f;
  if (tid < 128) h_s[tid] = 0.f;
  float xwv = XWb[tid];  // z-row for t=0 (x@Wr + br precomputed)
  __syncthreads();

  for (int t = 0; t < LL; t++) {
    float xw_n = (t + 1 < LL) ? XWb[(t + 1) * 512 + tid] : 0.f;  // prefetch
    v2f acc[4] = {{0.f, 0.f}, {0.f, 0.f}, {0.f, 0.f}, {0.f, 0.f}};
#pragma unroll
    for (int i4 = 0; i4 < 32; i4++) {  // full unroll: U[i4] must stay static
      float4 v = *(const float4*)&h_s[4 * i4];
      float4 w = U[i4];
      acc[i4 & 3] += (v2f){w.x, w.y} * (v2f){v.x, v.y};
      acc[i4 & 3] += (v2f){w.z, w.w} * (v2f){v.z, v.w};
    }
    v2f A = (acc[0] + acc[1]) + (acc[2] + acc[3]);
    pp_s[tid] = A.x + A.y + xwv;
    __syncthreads();
    if (tid < 128) {
      float zi = pp_s[tid], zf = pp_s[128 + tid], zg = pp_s[256 + tid], zo = pp_s[384 + tid];
      float ii = hsig(zi), ff = hsig(zf), gg = tanh_fast(zg), oo = hsig(zo);
      c_r = fmaf(ff, c_r, ii * gg);
      float h = oo * tanh_fast(c_r);
      h_s[tid] = h;
      ogb[t * 128 + tid] = h;
    }
    __syncthreads();
    xwv = xw_n;
  }
}

// ---- Writer: attention-memory scan, 1024 threads --------------------------
// z = ZW_t + m_rt@Vw + h@Uw. Thread (j = tid&511, half = tid>>9) computes
// the k-parity-half of column j's dots; halves merge in the gate stage.
// Uw: [0,NC) LDS + [NC,32) L2. Vw: streamed. mem: Mr[16] (row l=tid>>2,
// quarter qr=tid&3) + Mc[16] (rows (tid>>6)*16.., col pair tid&63).
template <int NC>
__global__ __launch_bounds__(1024, 4) void writer_kernel(
    const float* __restrict__ x,
    const float4* __restrict__ VwT4, const float4* __restrict__ UwT4,
    const float* __restrict__ og, const float* __restrict__ ZW,
    float* __restrict__ out) {
  alignas(16) __shared__ float h_s[128];
  alignas(16) __shared__ float osN[128];   // o_{t+1} (o_0 during prologue)
  alignas(16) __shared__ float sc_s[256], ee_s[256];
  alignas(16) __shared__ float mr_s[128];  // RAW col sums (no inv)
  alignas(16) __shared__ float pp_s[2048]; // S3: 16x128 m_rt partials; S5: 2x512 z halves
  __shared__ float rr_s[16];               // [0..3] wave max, [8..11] wave sum
  extern __shared__ float4 UwL[];          // NC*512 float4 Uw k-tile cache

  const int b = blockIdx.x, tid = threadIdx.x;
  const int lane = tid & 63, wv = tid >> 6;
  const int j = tid & 511, half = tid >> 9; // j-dot role
  const int l = tid >> 2, qr = tid & 3;     // Mr role: row l, col quarter qr
  const int q16 = tid >> 6, dp = tid & 63;  // Mc role: 16-row group, col pair

  const float* xg = x + (size_t)b * (LL * 128);
  const float* ogb = og + (size_t)b * (LL * 128);
  const float* ZWb = ZW + (size_t)b * (LL * 512);

  // stage Uw k-tiles [0,NC) into LDS once (144KB at NC=18)
  for (int i = tid; i < NC * 512; i += 1024) UwL[i] = UwT4[i];

  // register-resident mem, two layouts (fp32 pairs) — 64 VGPRs persistent.
  v2f Mr[16], Mc[16];
#pragma unroll
  for (int w = 0; w < 16; w++) Mr[w] = *(const v2f*)(xg + l * 128 + qr * 32 + 2 * w);
#pragma unroll
  for (int i = 0; i < 16; i++) Mc[i] = *(const v2f*)(xg + (q16 * 16 + i) * 128 + 2 * dp);

  float c_w = 0.f;  // live for tid<128 only
  if (tid < 128) { h_s[tid] = 0.f; osN[tid] = ogb[tid]; }
  __syncthreads();
  { // prologue: sc_s[l] = mem0[l] . o_0 (4-lane butterfly reduce)
    v2f S = {0.f, 0.f};
#pragma unroll
    for (int w = 0; w < 16; w++) S += Mr[w] * (*(const v2f*)&osN[qr * 32 + 2 * w]);
    float s = S.x + S.y;
    s += __shfl_xor(s, 1);
    s += __shfl_xor(s, 2);
    if (qr == 0) sc_s[l] = s;
  }
  __syncthreads();

  float zwv = (half == 0) ? ZWb[j] : 0.f;  // ZW row for t=0 (half0 carries it)
  for (int t = 0; t < LL; t++) {
    const int tn = (t + 1 < LL) ? t + 1 : t;
    float zw_n = (half == 0) ? ZWb[(size_t)tn * 512 + j] : 0.f;  // prefetch

    // S0: huv = zwv + (my k-parity-half of h_{t-1}@Uw).
    float huv;
    {
      v2f u0 = {0.f, 0.f}, u1 = {0.f, 0.f}, u2 = {0.f, 0.f}, u3 = {0.f, 0.f};
#pragma unroll 2
      for (int i4 = NC + half; i4 < 32; i4 += 2) {  // streamed Uw (L2)
        float4 w = UwT4[i4 * 512 + j];
        float4 v = *(const float4*)&h_s[4 * i4];
        u0 += (v2f){w.x, w.y} * (v2f){v.x, v.y};
        u1 += (v2f){w.z, w.w} * (v2f){v.z, v.w};
      }
#pragma unroll 2
      for (int i4 = half; i4 < NC; i4 += 2) {  // cached Uw (LDS)
        float4 w = UwL[i4 * 512 + j];
        float4 v = *(const float4*)&h_s[4 * i4];
        u2 += (v2f){w.x, w.y} * (v2f){v.x, v.y};
        u3 += (v2f){w.z, w.w} * (v2f){v.z, v.w};
      }
      v2f U = (u0 + u1) + (u2 + u3);
      huv = U.x + U.y + zwv;
    }

    // A: single-pass local softmax (per-wave max + exp + sum) ∥ osN load
    if (tid >= 128 && tid < 256 && t + 1 < LL)
      osN[tid - 128] = ogb[(t + 1) * 128 + (tid - 128)];
    if (tid < 256) {
      float s = sc_s[tid];
      float m = s;
#pragma unroll
      for (int off = 32; off > 0; off >>= 1) m = fmaxf(m, __shfl_xor(m, off));
      float e = __expf(s - m);   // wave-relative exp, <= 1
      ee_s[tid] = e;             // RAW (wave-relative) — consumers apply f
      float s2 = e;
#pragma unroll
      for (int off = 32; off > 0; off >>= 1) s2 += __shfl_xor(s2, off);
      if (lane == 0) { rr_s[wv] = m; rr_s[8 + wv] = s2; }
    }
    __syncthreads();  // bar1

    // B: fold global max/sum. Both Mr's row-block (l>>6) and Mc's row-block
    // (q16>>2) equal tid>>8 -> ONE f/fzi per thread, v5's exact expressions.
    const float M = fmaxf(fmaxf(rr_s[0], rr_s[1]), fmaxf(rr_s[2], rr_s[3]));
    const float Sg = rr_s[8] * __expf(rr_s[0] - M) + rr_s[9] * __expf(rr_s[1] - M) +
                     rr_s[10] * __expf(rr_s[2] - M) + rr_s[11] * __expf(rr_s[3] - M);
    const float inv = 1.f / Sg;
    const float f = __expf(rr_s[tid >> 8] - M);
    const float fzi = f * inv;

    // S3: m_rt partials (col-major, register-local), scaled by f
    {
      v2f P0 = {0.f, 0.f}, P1 = {0.f, 0.f};
#pragma unroll
      for (int i = 0; i < 16; i += 2) {
        P0 += Mc[i] * ee_s[q16 * 16 + i];
        P1 += Mc[i + 1] * ee_s[q16 * 16 + i + 1];
      }
      v2f P = (P0 + P1) * f;
      *(v2f*)&pp_s[q16 * 128 + 2 * dp] = P;
    }
    __syncthreads();  // bar2
    // S4: raw m_rt (inv folded in S5)
    if (tid < 128) {
      float s = 0.f;
#pragma unroll
      for (int g8 = 0; g8 < 16; g8++) s += pp_s[g8 * 128 + tid];
      mr_s[tid] = s;
    }
    __syncthreads();  // bar3
    // S5: z-half: pp_s[half*512+j] = huv + inv*(my half of mraw@Vw)
    {
      v2f a0 = {0.f, 0.f}, a1 = {0.f, 0.f};
#pragma unroll 4
      for (int i4 = half; i4 < 32; i4 += 2) {  // streamed Vw (L2)
        float4 w = VwT4[i4 * 512 + j];
        float4 v = *(const float4*)&mr_s[4 * i4];
        a0 += (v2f){w.x, w.y} * (v2f){v.x, v.y};
        a1 += (v2f){w.z, w.w} * (v2f){v.z, v.w};
      }
      v2f A = a0 + a1;
      pp_s[half * 512 + j] = fmaf(A.x + A.y, inv, huv);
    }
    __syncthreads();  // bar4
    // S6: gates (merge the two z-halves)
    if (tid < 128) {
      float zi = pp_s[tid] + pp_s[512 + tid];
      float zf = pp_s[128 + tid] + pp_s[640 + tid];
      float zg = pp_s[256 + tid] + pp_s[768 + tid];
      float zo = pp_s[384 + tid] + pp_s[896 + tid];
      float ii = hsig(zi), ff = hsig(zf), gg = tanh_fast(zg), oo = hsig(zo);
      c_w = fmaf(ff, c_w, ii * gg);
      h_s[tid] = oo * tanh_fast(c_w);
    }
    __syncthreads();  // bar5
    // S7: mem update (both layouts, z = ee*fzi) + fused next scores
    if (t + 1 < LL) {
      const float zr = ee_s[l] * fzi;
      v2f S0v = {0.f, 0.f}, S1v = {0.f, 0.f};
#pragma unroll
      for (int w = 0; w < 16; w += 2) {
        v2f h2a = *(const v2f*)&h_s[qr * 32 + 2 * w];
        v2f ma = Mr[w];
        v2f na = ma + (h2a - ma) * zr;
        Mr[w] = na;
        S0v += na * (*(const v2f*)&osN[qr * 32 + 2 * w]);
        v2f h2b = *(const v2f*)&h_s[qr * 32 + 2 * (w + 1)];
        v2f mb = Mr[w + 1];
        v2f nb = mb + (h2b - mb) * zr;
        Mr[w + 1] = nb;
        S1v += nb * (*(const v2f*)&osN[qr * 32 + 2 * (w + 1)]);
      }
      v2f Sv = S0v + S1v;
      float s = Sv.x + Sv.y;
      s += __shfl_xor(s, 1);
      s += __shfl_xor(s, 2);
      if (qr == 0) sc_s[l] = s;
      v2f hc = *(const v2f*)&h_s[2 * dp];
#pragma unroll
      for (int i = 0; i < 16; i++) {
        float zc = ee_s[q16 * 16 + i] * fzi;  // same expr shape as zr
        v2f m = Mc[i];
        Mc[i] = m + (hc - m) * zc;
      }
    }
    __syncthreads();  // bar6
    zwv = zw_n;
  }

  if (tid < 128) out[b * 128 + tid] = h_s[tid];
}

extern "C" void kernel_launch(void* const* d_in, const int* in_sizes, int n_in,
                              void* d_out, int out_size, void* d_ws, size_t ws_size,
                              hipStream_t stream) {
  const float* x  = (const float*)d_in[0];
  const float* Wr = (const float*)d_in[1];
  const float* Ur = (const float*)d_in[2];
  const float* br = (const float*)d_in[3];
  const float* Ww = (const float*)d_in[4];
  const float* Uw = (const float*)d_in[5];
  const float* bw = (const float*)d_in[6];
  const float* Wc = (const float*)d_in[7];
  const float* bc = (const float*)d_in[8];
  float* out = (float*)d_out;

  // workspace (floats): og 1,048,576 | XW/ZW 4,194,304 | WrT 65,536 |
  // UrT 65,536 | UwT 65,536 | PVw 131,072 | PwT 65,536 | VwT 65,536 | pz 512
  // total 5,702,656 floats = 22.8 MB
  float* og  = (float*)d_ws;
  float* XW  = og + 1048576;   // ZW aliases XW (XW dead after reader)
  float* WrT = XW + 4194304;
  float* UrT = WrT + 65536;
  float* UwT = UrT + 65536;
  float* PVw = UwT + 65536;
  float* PwT = PVw + 131072;
  float* VwT = PwT + 65536;
  float* pz  = VwT + 65536;

  // big-LDS opt-in for the Uw cache (capture-safe: not a stream op).
  static int nc_cached = -1;
  if (nc_cached < 0) {
    int want = 18 * 512 * (int)sizeof(float4);  // 147456 B dynamic
    nc_cached = (hipFuncSetAttribute(
                     reinterpret_cast<const void*>(&writer_kernel<18>),
                     hipFuncAttributeMaxDynamicSharedMemorySize, want) == hipSuccess)
                    ? 18
                    : 6;  // fallback: 48KB dynamic, under default 64KB limit
  }

  wtrans_kernel<<<128, 512, 0, stream>>>(Wr, WrT, 9);
  wtrans_kernel<<<128, 512, 0, stream>>>(Ur, UrT, 9);
  wtrans_kernel<<<128, 512, 0, stream>>>(Uw, UwT, 9);
  pvw_gemm<<<256, 512, 0, stream>>>(Wc, Ww, PVw);
  pz_kernel<<<1, 512, 0, stream>>>(bc, Ww, bw, pz);
  wtrans_kernel<<<128, 512, 0, stream>>>(PVw, PwT, 9);
  wtrans_kernel<<<128, 512, 0, stream>>>(PVw + 65536, VwT, 9);
  xw_gemm<<<1024, 512, 0, stream>>>(x, (const float4*)WrT, br, XW);
  reader_kernel<<<32, 512, 0, stream>>>((const float4*)UrT, XW, og);
  xw_gemm<<<1024, 512, 0, stream>>>(og, (const float4*)PwT, pz, XW);  // ZW
  if (nc_cached == 18) {
    writer_kernel<18><<<32, 1024, 18 * 512 * sizeof(float4), stream>>>(
        x, (const float4*)VwT, (const float4*)UwT, og, XW, out);
  } else {
    writer_kernel<6><<<32, 1024, 6 * 512 * sizeof(float4), stream>>>(
        x, (const float4*)VwT, (const float4*)UwT, og, XW, out);
  }
}

// Round 10
// 2030.204 us; speedup vs baseline: 1.6770x; 1.2395x over previous
//
#include <hip/hip_runtime.h>
#include <stdint.h>

// B=32, L=256, D=128. Reader LSTM scan + attention-memory writer scan. FP32.
// Inputs: x(32,256,128), Wr(128,512), Ur(128,512), br(512),
//         Ww(128,512), Uw(128,512), bw(512), Wc(256,128), bc(128)
// Output: final writer h (32,128) fp32.
//
// v10 = v7 MINUS VR[16]: the clean A/B of {single-pass softmax (6 barriers),
// ZW 1-step prefetch, split FMA chains} at exactly v5's register pressure.
// History: v5 writer=1543 clean; v7 (these + VR[16]) spilled 1MB -> 1711;
// v9 (1024thr) spilled mem itself -> 2163. Register law: Mr64+Mc64 only.
// S0 (h@Uw) = 18 LDS tiles + 14 L2-streamed. S5: all 32 Vw tiles streamed
// (v5's "VR in regs" was rematerialized to loads anyway — FETCH identical).
// WRITE_SIZE = spill canary (must be 16KB).
// Workspace: 5.70M floats = 22.8MB (ZW aliases XW; XW dead after reader).

#define LL 256

typedef float v2f __attribute__((ext_vector_type(2)));

__device__ __forceinline__ float hsig(float x) { return fminf(fmaxf(fmaf(x, 0.2f, 0.5f), 0.f), 1.f); }
__device__ __forceinline__ float tanh_fast(float x) {
  x = fminf(fmaxf(x, -15.f), 15.f);
  float e = __expf(2.f * x);
  return (e - 1.f) / (e + 1.f);
}

// ---- Prep: transpose fp32 W[K][J] (row-major) -> float4 k-tiles ----------
// dst float4 index (k>>2)*J + j holds rows k..k+3 of column j.
__global__ __launch_bounds__(512) void wtrans_kernel(const float* __restrict__ src,
                                                     float* __restrict__ dst, int jshift) {
  int idx = blockIdx.x * 512 + threadIdx.x;
  int J = 1 << jshift;
  int k = idx >> jshift, j = idx & (J - 1);
  dst[(((size_t)(k >> 2) << jshift) + j) * 4 + (k & 3)] = src[idx];
}

// ---- PVw[r][j] = Wc[r][:] @ Ww[:,j]  (r<128: Pw=Wc_top@Ww, r>=128: Vw) ----
__global__ __launch_bounds__(512) void pvw_gemm(const float* __restrict__ Wc,
                                                const float* __restrict__ Ww,
                                                float* __restrict__ PVw) {
  __shared__ float wrow[128];
  const int r = blockIdx.x, j = threadIdx.x;
  if (j < 128) wrow[j] = Wc[r * 128 + j];
  __syncthreads();
  float a = 0.f;
#pragma unroll 4
  for (int m = 0; m < 128; m++) a = fmaf(wrow[m], Ww[m * 512 + j], a);
  PVw[r * 512 + j] = a;
}

// ---- pz[j] = bc @ Ww[:,j] + bw[j] -----------------------------------------
__global__ __launch_bounds__(512) void pz_kernel(const float* __restrict__ bc,
                                                 const float* __restrict__ Ww,
                                                 const float* __restrict__ bw,
                                                 float* __restrict__ pz) {
  __shared__ float b_s[128];
  const int j = threadIdx.x;
  if (j < 128) b_s[j] = bc[j];
  __syncthreads();
  float a = bw[j];
#pragma unroll 4
  for (int m = 0; m < 128; m++) a = fmaf(b_s[m], Ww[m * 512 + j], a);
  pz[j] = a;
}

// ---- GEMM: OUT[b,t,:] = IN[b,t,:] @ W(T4 tiles, K=128,J=512) + bias -------
// Used for XW = x@Wr + br  and  ZW = og@Pw + pz.
__global__ __launch_bounds__(512) void xw_gemm(const float* __restrict__ x,
                                               const float4* __restrict__ WrT4,
                                               const float* __restrict__ br,
                                               float* __restrict__ XW) {
  alignas(16) __shared__ float xs[8][128];
  const int b = blockIdx.x >> 5, tg = blockIdx.x & 31, tid = threadIdx.x;
  const float* xg = x + ((size_t)b * LL + tg * 8) * 128;
  if (tid < 256) ((float4*)&xs[0][0])[tid] = ((const float4*)xg)[tid];
  __syncthreads();
  float acc[8];
#pragma unroll
  for (int r = 0; r < 8; r++) acc[r] = 0.f;
#pragma unroll 8
  for (int i4 = 0; i4 < 32; i4++) {
    float4 w4 = WrT4[i4 * 512 + tid];
#pragma unroll
    for (int r = 0; r < 8; r++) {
      float4 v = *(const float4*)&xs[r][4 * i4];
      acc[r] += w4.x * v.x + w4.y * v.y + w4.z * v.z + w4.w * v.w;
    }
  }
  const float brj = br[tid];
  float* o = XW + ((size_t)b * LL + tg * 8) * 512;
#pragma unroll
  for (int r = 0; r < 8; r++) o[r * 512 + tid] = acc[r] + brj;
}

// ---- Reader: sequential LSTM scan, Ur register-resident -------------------
__global__ __launch_bounds__(512, 2) void reader_kernel(const float4* __restrict__ UrT4,
                                                        const float* __restrict__ XW,
                                                        float* __restrict__ og) {
  alignas(16) __shared__ float h_s[128];
  alignas(16) __shared__ float pp_s[512];
  const int b = blockIdx.x, tid = threadIdx.x;
  const float* XWb = XW + (size_t)b * LL * 512;
  float* ogb = og + (size_t)b * LL * 128;

  float4 U[32];  // column tid of Ur, held for the whole scan (128 VGPRs)
#pragma unroll
  for (int i4 = 0; i4 < 32; i4++) U[i4] = UrT4[i4 * 512 + tid];

  float c_r = 0.f;
  if (tid < 128) h_s[tid] = 0.f;
  float xwv = XWb[tid];  // z-row for t=0 (x@Wr + br precomputed)
  __syncthreads();

  for (int t = 0; t < LL; t++) {
    float xw_n = (t + 1 < LL) ? XWb[(t + 1) * 512 + tid] : 0.f;  // prefetch
    v2f acc[4] = {{0.f, 0.f}, {0.f, 0.f}, {0.f, 0.f}, {0.f, 0.f}};
#pragma unroll
    for (int i4 = 0; i4 < 32; i4++) {  // full unroll: U[i4] must stay static
      float4 v = *(const float4*)&h_s[4 * i4];
      float4 w = U[i4];
      acc[i4 & 3] += (v2f){w.x, w.y} * (v2f){v.x, v.y};
      acc[i4 & 3] += (v2f){w.z, w.w} * (v2f){v.z, v.w};
    }
    v2f A = (acc[0] + acc[1]) + (acc[2] + acc[3]);
    pp_s[tid] = A.x + A.y + xwv;
    __syncthreads();
    if (tid < 128) {
      float zi = pp_s[tid], zf = pp_s[128 + tid], zg = pp_s[256 + tid], zo = pp_s[384 + tid];
      float ii = hsig(zi), ff = hsig(zf), gg = tanh_fast(zg), oo = hsig(zo);
      c_r = fmaf(ff, c_r, ii * gg);
      float h = oo * tanh_fast(c_r);
      h_s[tid] = h;
      ogb[t * 128 + tid] = h;
    }
    __syncthreads();
    xwv = xw_n;
  }
}

// ---- Writer: attention-memory scan ---------------------------------------
// z = ZW_t + m_rt@Vw + h@Uw. Uw: [0,NC) LDS + [NC,32) L2 (at loop top,
// h = h_{t-1}). Vw: fully streamed. Single-pass softmax; ZW prefetch.
template <int NC>
__global__ __launch_bounds__(512, 2) void writer_kernel(
    const float* __restrict__ x,
    const float4* __restrict__ VwT4, const float4* __restrict__ UwT4,
    const float* __restrict__ og, const float* __restrict__ ZW,
    float* __restrict__ out) {
  alignas(16) __shared__ float h_s[128];
  alignas(16) __shared__ float osN[128];   // o_{t+1} (o_0 during prologue)
  alignas(16) __shared__ float sc_s[256], ee_s[256];
  alignas(16) __shared__ float mr_s[128];  // RAW col sums (no inv)
  alignas(16) __shared__ float pp_s[1024];
  __shared__ float rr_s[16];               // [0..3] wave max, [8..11] wave sum
  extern __shared__ float4 UwL[];          // NC*512 float4 Uw k-tile cache

  const int b = blockIdx.x, tid = threadIdx.x;
  const int lane = tid & 63, wv = tid >> 6;
  const int l = tid >> 1, hf = tid & 1;    // row-major role
  const int q = tid >> 6, dp = tid & 63;   // col-major role

  const float* xg = x + (size_t)b * (LL * 128);
  const float* ogb = og + (size_t)b * (LL * 128);
  const float* ZWb = ZW + (size_t)b * (LL * 512);

  // stage Uw k-tiles [0,NC) into LDS once (144KB at NC=18)
  for (int i = tid; i < NC * 512; i += 512) UwL[i] = UwT4[i];

  // register-resident mem, two layouts (fp32 pairs) — THE register budget.
  v2f Mr[32], Mc[32];
#pragma unroll
  for (int w = 0; w < 32; w++) Mr[w] = *(const v2f*)(xg + l * 128 + hf * 64 + 2 * w);
#pragma unroll
  for (int i = 0; i < 32; i++) Mc[i] = *(const v2f*)(xg + (q * 32 + i) * 128 + 2 * dp);

  float c_w = 0.f;
  if (tid < 128) { h_s[tid] = 0.f; osN[tid] = ogb[tid]; }
  __syncthreads();
  { // prologue: sc_s[l] = mem0[l] . o_0
    v2f S = {0.f, 0.f};
#pragma unroll
    for (int w = 0; w < 32; w++) S += Mr[w] * (*(const v2f*)&osN[hf * 64 + 2 * w]);
    float s = S.x + S.y;
    s += __shfl_xor(s, 1);
    if (hf == 0) sc_s[l] = s;
  }
  __syncthreads();

  float zwv = ZWb[tid];  // ZW row for t=0
  for (int t = 0; t < LL; t++) {
    const int tn = (t + 1 < LL) ? t + 1 : t;
    float zw_n = ZWb[(size_t)tn * 512 + tid];  // prefetch next ZW row

    // S0: huv = zwv + h_{t-1}@Uw — NC LDS tiles + (32-NC) streamed L2 tiles.
    float huv;
    {
      v2f u0 = {0.f, 0.f}, u1 = {0.f, 0.f}, u2 = {0.f, 0.f}, u3 = {0.f, 0.f};
#pragma unroll 2
      for (int i4 = NC; i4 < 32; i4 += 2) {  // streamed Uw (L2)
        float4 w0 = UwT4[i4 * 512 + tid];
        float4 w1 = UwT4[(i4 + 1) * 512 + tid];
        float4 v0 = *(const float4*)&h_s[4 * i4];
        float4 v1 = *(const float4*)&h_s[4 * i4 + 4];
        u0 += (v2f){w0.x, w0.y} * (v2f){v0.x, v0.y};
        u0 += (v2f){w0.z, w0.w} * (v2f){v0.z, v0.w};
        u1 += (v2f){w1.x, w1.y} * (v2f){v1.x, v1.y};
        u1 += (v2f){w1.z, w1.w} * (v2f){v1.z, v1.w};
      }
#pragma unroll 2
      for (int i4 = 0; i4 < NC; i4++) {  // cached Uw (LDS)
        float4 w = UwL[i4 * 512 + tid];
        float4 v = *(const float4*)&h_s[4 * i4];
        u2 += (v2f){w.x, w.y} * (v2f){v.x, v.y};
        u3 += (v2f){w.z, w.w} * (v2f){v.z, v.w};
      }
      v2f U = (u0 + u1) + (u2 + u3);
      huv = U.x + U.y + zwv;
    }

    // A: single-pass local softmax (per-wave max + exp + sum) ∥ osN load
    if (tid >= 128 && tid < 256 && t + 1 < LL)
      osN[tid - 128] = ogb[(t + 1) * 128 + (tid - 128)];
    if (tid < 256) {
      float s = sc_s[tid];
      float m = s;
#pragma unroll
      for (int off = 32; off > 0; off >>= 1) m = fmaxf(m, __shfl_xor(m, off));
      float e = __expf(s - m);   // wave-relative exp, <= 1
      ee_s[tid] = e;             // RAW (wave-relative) — consumers apply f
      float s2 = e;
#pragma unroll
      for (int off = 32; off > 0; off >>= 1) s2 += __shfl_xor(s2, off);
      if (lane == 0) { rr_s[wv] = m; rr_s[8 + wv] = s2; }
    }
    __syncthreads();  // bar1

    // B: fold global max/sum; per-thread factor f (wave tid>>7 of sc-space —
    // serves BOTH S3's group (q>>1) and S7's row (l>>6), which equal tid>>7).
    const float M = fmaxf(fmaxf(rr_s[0], rr_s[1]), fmaxf(rr_s[2], rr_s[3]));
    const float Sg = rr_s[8] * __expf(rr_s[0] - M) + rr_s[9] * __expf(rr_s[1] - M) +
                     rr_s[10] * __expf(rr_s[2] - M) + rr_s[11] * __expf(rr_s[3] - M);
    const float inv = 1.f / Sg;
    const float f = __expf(rr_s[tid >> 7] - M);
    const float fzi = f * inv;

    // S3: m_rt partials (col-major, register-local), 2 chains, scaled by f
    {
      v2f P0 = {0.f, 0.f}, P1 = {0.f, 0.f};
#pragma unroll
      for (int i = 0; i < 32; i += 2) {
        P0 += Mc[i] * ee_s[q * 32 + i];
        P1 += Mc[i + 1] * ee_s[q * 32 + i + 1];
      }
      v2f P = (P0 + P1) * f;
      *(v2f*)&pp_s[q * 128 + 2 * dp] = P;
    }
    __syncthreads();  // bar2
    // S4: raw m_rt (inv folded later, scalar, in S5)
    if (tid < 128) {
      float s = 0.f;
#pragma unroll
      for (int g8 = 0; g8 < 8; g8++) s += pp_s[g8 * 128 + tid];
      mr_s[tid] = s;
    }
    __syncthreads();  // bar3
    // S5: z[j] = huv + inv*(mraw@Vw) — all 32 tiles streamed (L2).
    {
      v2f a0 = {0.f, 0.f}, a1 = {0.f, 0.f}, a2 = {0.f, 0.f}, a3 = {0.f, 0.f};
#pragma unroll 2
      for (int i4 = 0; i4 < 32; i4 += 4) {
        float4 w0 = VwT4[i4 * 512 + tid];
        float4 w1 = VwT4[(i4 + 1) * 512 + tid];
        float4 w2 = VwT4[(i4 + 2) * 512 + tid];
        float4 w3 = VwT4[(i4 + 3) * 512 + tid];
        float4 v0 = *(const float4*)&mr_s[4 * i4];
        float4 v1 = *(const float4*)&mr_s[4 * i4 + 4];
        float4 v2 = *(const float4*)&mr_s[4 * i4 + 8];
        float4 v3 = *(const float4*)&mr_s[4 * i4 + 12];
        a0 += (v2f){w0.x, w0.y} * (v2f){v0.x, v0.y};
        a0 += (v2f){w0.z, w0.w} * (v2f){v0.z, v0.w};
        a1 += (v2f){w1.x, w1.y} * (v2f){v1.x, v1.y};
        a1 += (v2f){w1.z, w1.w} * (v2f){v1.z, v1.w};
        a2 += (v2f){w2.x, w2.y} * (v2f){v2.x, v2.y};
        a2 += (v2f){w2.z, w2.w} * (v2f){v2.z, v2.w};
        a3 += (v2f){w3.x, w3.y} * (v2f){v3.x, v3.y};
        a3 += (v2f){w3.z, w3.w} * (v2f){v3.z, v3.w};
      }
      v2f A = (a0 + a2) + (a1 + a3);
      pp_s[tid] = fmaf(A.x + A.y, inv, huv);
    }
    __syncthreads();  // bar4
    // S6: gates
    if (tid < 128) {
      float zi = pp_s[tid], zf = pp_s[128 + tid], zg = pp_s[256 + tid], zo = pp_s[384 + tid];
      float ii = hsig(zi), ff = hsig(zf), gg = tanh_fast(zg), oo = hsig(zo);
      c_w = fmaf(ff, c_w, ii * gg);
      h_s[tid] = oo * tanh_fast(c_w);
    }
    __syncthreads();  // bar5
    // S7: mem update (both layouts, bit-identical z = ee*fzi) + next scores
    if (t + 1 < LL) {
      const float zr = ee_s[l] * fzi;
      v2f S0v = {0.f, 0.f}, S1v = {0.f, 0.f};
#pragma unroll
      for (int w = 0; w < 32; w += 2) {
        v2f h2a = *(const v2f*)&h_s[hf * 64 + 2 * w];
        v2f ma = Mr[w];
        v2f na = ma + (h2a - ma) * zr;
        Mr[w] = na;
        S0v += na * (*(const v2f*)&osN[hf * 64 + 2 * w]);
        v2f h2b = *(const v2f*)&h_s[hf * 64 + 2 * (w + 1)];
        v2f mb = Mr[w + 1];
        v2f nb = mb + (h2b - mb) * zr;
        Mr[w + 1] = nb;
        S1v += nb * (*(const v2f*)&osN[hf * 64 + 2 * (w + 1)]);
      }
      v2f Sv = S0v + S1v;
      float s = Sv.x + Sv.y;
      s += __shfl_xor(s, 1);
      if (hf == 0) sc_s[l] = s;
      v2f hc = *(const v2f*)&h_s[2 * dp];
#pragma unroll
      for (int i = 0; i < 32; i++) {
        float zc = ee_s[q * 32 + i] * fzi;  // same expr shape as zr
        v2f m = Mc[i];
        Mc[i] = m + (hc - m) * zc;
      }
    }
    __syncthreads();  // bar6
    zwv = zw_n;
  }

  if (tid < 128) out[b * 128 + tid] = h_s[tid];
}

extern "C" void kernel_launch(void* const* d_in, const int* in_sizes, int n_in,
                              void* d_out, int out_size, void* d_ws, size_t ws_size,
                              hipStream_t stream) {
  const float* x  = (const float*)d_in[0];
  const float* Wr = (const float*)d_in[1];
  const float* Ur = (const float*)d_in[2];
  const float* br = (const float*)d_in[3];
  const float* Ww = (const float*)d_in[4];
  const float* Uw = (const float*)d_in[5];
  const float* bw = (const float*)d_in[6];
  const float* Wc = (const float*)d_in[7];
  const float* bc = (const float*)d_in[8];
  float* out = (float*)d_out;

  // workspace (floats): og 1,048,576 | XW/ZW 4,194,304 | WrT 65,536 |
  // UrT 65,536 | UwT 65,536 | PVw 131,072 | PwT 65,536 | VwT 65,536 | pz 512
  // total 5,702,656 floats = 22.8 MB
  float* og  = (float*)d_ws;
  float* XW  = og + 1048576;   // ZW aliases XW (XW dead after reader)
  float* WrT = XW + 4194304;
  float* UrT = WrT + 65536;
  float* UwT = UrT + 65536;
  float* PVw = UwT + 65536;
  float* PwT = PVw + 131072;
  float* VwT = PwT + 65536;
  float* pz  = VwT + 65536;

  // big-LDS opt-in for the Uw cache (capture-safe: not a stream op).
  static int nc_cached = -1;
  if (nc_cached < 0) {
    int want = 18 * 512 * (int)sizeof(float4);  // 147456 B dynamic
    nc_cached = (hipFuncSetAttribute(
                     reinterpret_cast<const void*>(&writer_kernel<18>),
                     hipFuncAttributeMaxDynamicSharedMemorySize, want) == hipSuccess)
                    ? 18
                    : 6;  // fallback: 48KB dynamic, under default 64KB limit
  }

  wtrans_kernel<<<128, 512, 0, stream>>>(Wr, WrT, 9);
  wtrans_kernel<<<128, 512, 0, stream>>>(Ur, UrT, 9);
  wtrans_kernel<<<128, 512, 0, stream>>>(Uw, UwT, 9);
  pvw_gemm<<<256, 512, 0, stream>>>(Wc, Ww, PVw);
  pz_kernel<<<1, 512, 0, stream>>>(bc, Ww, bw, pz);
  wtrans_kernel<<<128, 512, 0, stream>>>(PVw, PwT, 9);
  wtrans_kernel<<<128, 512, 0, stream>>>(PVw + 65536, VwT, 9);
  xw_gemm<<<1024, 512, 0, stream>>>(x, (const float4*)WrT, br, XW);
  reader_kernel<<<32, 512, 0, stream>>>((const float4*)UrT, XW, og);
  xw_gemm<<<1024, 512, 0, stream>>>(og, (const float4*)PwT, pz, XW);  // ZW
  if (nc_cached == 18) {
    writer_kernel<18><<<32, 512, 18 * 512 * sizeof(float4), stream>>>(
        x, (const float4*)VwT, (const float4*)UwT, og, XW, out);
  } else {
    writer_kernel<6><<<32, 512, 6 * 512 * sizeof(float4), stream>>>(
        x, (const float4*)VwT, (const float4*)UwT, og, XW, out);
  }
}